// Round 1
// baseline (1821.374 us; speedup 1.0000x reference)
//
#include <hip/hip_runtime.h>
#include <hip/hip_bf16.h>
#include <math.h>

typedef __bf16 bf16;
typedef __bf16 bf16x8 __attribute__((ext_vector_type(8)));
typedef float f32x4 __attribute__((ext_vector_type(4)));

#define NB 64
#define NW 100
#define NL 3
#define NDF 172
#define DGRU 688
#define DGRUP 704
#define NTOK 19200   // NB*NW*NL
#define NROW 6400    // NB*NW
#define HDC 86       // DGRU/8

// ---------------- conversion with K zero-padding ----------------
__global__ void k_cvt_pad(const float* __restrict__ src, bf16* __restrict__ dst,
                          int R, int K, int Kp) {
  int stride = gridDim.x * blockDim.x;
  for (int i = blockIdx.x * blockDim.x + threadIdx.x; i < R * Kp; i += stride) {
    int r = i / Kp, c = i - r * Kp;
    float v = (c < K) ? src[(size_t)r * K + c] : 0.f;
    dst[i] = (bf16)v;
  }
}

// ---------------- build X = [edge_f | time_f | src_nf | tgt_nf] ----------------
__global__ void k_build_X(const float* __restrict__ node_table, const float* __restrict__ edge_table,
                          const float* __restrict__ basis_freq, const float* __restrict__ phase,
                          const int* __restrict__ node_idx, const int* __restrict__ edge_idx,
                          const float* __restrict__ time_idx,
                          float* __restrict__ Xf, bf16* __restrict__ Xb) {
  int row = blockIdx.x;              // (b*NW + w)*NL + l
  int nw = row / NL;
  int l = row - nw * NL;
  int e = edge_idx[nw * NL + l];
  int sn = node_idx[nw * 2 * NL + 2 * l];
  int tn = node_idx[nw * 2 * NL + 2 * l + 1];
  float dt = time_idx[nw * NL + (NL - 1)] - time_idx[nw * NL + l];
  const float* ep = edge_table + (size_t)e * NDF;
  const float* sp = node_table + (size_t)sn * NDF;
  const float* tp = node_table + (size_t)tn * NDF;
  float* xr = Xf + (size_t)row * DGRU;
  bf16* xb = Xb + (size_t)row * DGRUP;
  for (int c = threadIdx.x; c < DGRUP; c += blockDim.x) {
    float v = 0.f;
    if (c < NDF) v = ep[c];
    else if (c < 2 * NDF) { int k = c - NDF; v = cosf(dt * basis_freq[k] + phase[k]); }
    else if (c < 3 * NDF) v = sp[c - 2 * NDF];
    else if (c < DGRU) v = tp[c - 3 * NDF];
    if (c < DGRU) xr[c] = v;
    xb[c] = (bf16)v;
  }
}

// ---------------- generic bf16 MFMA GEMM: C = A @ W^T (+bias)(+relu) ----------------
// A: (M, Kp) bf16 row-major; W: (N, Kp) bf16 row-major; C f32 and/or bf16, ld = N.
#define BM 128
#define BN 128
#define BKK 32
#define LSTR 48

__global__ __launch_bounds__(256, 2) void k_gemm(
    const bf16* __restrict__ A, const bf16* __restrict__ Bw,
    const float* __restrict__ bias,
    float* __restrict__ Cf, bf16* __restrict__ Cb,
    int M, int N, int Kp, int relu) {
  __shared__ __align__(16) bf16 sA[BM * LSTR];
  __shared__ __align__(16) bf16 sB[BN * LSTR];
  const int m0 = blockIdx.y * BM;
  const int n0 = blockIdx.x * BN;
  const int tid = threadIdx.x;
  const int lane = tid & 63;
  const int wv = tid >> 6;
  const int wr = wv >> 1, wc = wv & 1;
  const int rr = lane & 15;
  const int kq = (lane >> 4) * 8;
  f32x4 acc[4][4] = {};
  for (int k0 = 0; k0 < Kp; k0 += BKK) {
    __syncthreads();
    for (int c = tid; c < 512; c += 256) {
      int row = c >> 2, kc = c & 3;
      *(uint4*)(&sA[row * LSTR + kc * 8]) =
          *(const uint4*)(A + (size_t)(m0 + row) * Kp + k0 + kc * 8);
    }
    for (int c = tid; c < 512; c += 256) {
      int row = c >> 2, kc = c & 3;
      uint4 v = make_uint4(0u, 0u, 0u, 0u);
      if (n0 + row < N)
        v = *(const uint4*)(Bw + (size_t)(n0 + row) * Kp + k0 + kc * 8);
      *(uint4*)(&sB[row * LSTR + kc * 8]) = v;
    }
    __syncthreads();
    bf16x8 af[4], bfr[4];
#pragma unroll
    for (int i = 0; i < 4; i++) {
      af[i]  = *(const bf16x8*)(&sA[(wr * 64 + i * 16 + rr) * LSTR + kq]);
      bfr[i] = *(const bf16x8*)(&sB[(wc * 64 + i * 16 + rr) * LSTR + kq]);
    }
#pragma unroll
    for (int i = 0; i < 4; i++)
#pragma unroll
      for (int j = 0; j < 4; j++)
        acc[i][j] = __builtin_amdgcn_mfma_f32_16x16x32_bf16(af[i], bfr[j], acc[i][j], 0, 0, 0);
  }
  const int cq = lane & 15, rq = lane >> 4;
#pragma unroll
  for (int i = 0; i < 4; i++) {
#pragma unroll
    for (int j = 0; j < 4; j++) {
      int col = n0 + wc * 64 + j * 16 + cq;
      if (col >= N) continue;
      float bv = bias ? bias[col] : 0.f;
      int row0 = m0 + wr * 64 + i * 16 + rq * 4;
#pragma unroll
      for (int r = 0; r < 4; r++) {
        float v = acc[i][j][r] + bv;
        if (relu) v = fmaxf(v, 0.f);
        size_t idx = (size_t)(row0 + r) * N + col;
        if (Cf) Cf[idx] = v;
        if (Cb) Cb[idx] = (bf16)v;
      }
    }
  }
}

// ---------------- cat attention: L=3, 8 heads, hd=86, f32 ----------------
__global__ void k_attn_cat(const float* __restrict__ QKV, bf16* __restrict__ out) {
  __shared__ float sq[NL][DGRU], sk[NL][DGRU], sv[NL][DGRU];
  __shared__ float sp[8][NL][NL];
  int n = blockIdx.x;
  const float* basep = QKV + (size_t)n * NL * (3 * DGRU);
  for (int idx = threadIdx.x; idx < NL * DGRU; idx += blockDim.x) {
    int l = idx / DGRU, c = idx - l * DGRU;
    sq[l][c] = basep[l * 3 * DGRU + c];
    sk[l][c] = basep[l * 3 * DGRU + DGRU + c];
    sv[l][c] = basep[l * 3 * DGRU + 2 * DGRU + c];
  }
  __syncthreads();
  if (threadIdx.x < 72) {
    int h = threadIdx.x / 9, rem = threadIdx.x % 9;
    int i = rem / 3, j = rem - i * 3;
    float s = 0.f;
    const float* qp = &sq[i][h * HDC];
    const float* kp = &sk[j][h * HDC];
    for (int d = 0; d < HDC; d++) s += qp[d] * kp[d];
    sp[h][i][j] = s * 0.10783277320343841f;  // 1/sqrt(86)
  }
  __syncthreads();
  if (threadIdx.x < 24) {
    int h = threadIdx.x / 3, i = threadIdx.x - h * 3;
    float a0 = sp[h][i][0], a1 = sp[h][i][1], a2 = sp[h][i][2];
    float mx = fmaxf(a0, fmaxf(a1, a2));
    float e0 = expf(a0 - mx), e1 = expf(a1 - mx), e2 = expf(a2 - mx);
    float inv = 1.f / (e0 + e1 + e2);
    sp[h][i][0] = e0 * inv; sp[h][i][1] = e1 * inv; sp[h][i][2] = e2 * inv;
  }
  __syncthreads();
  bf16* orow = out + (size_t)n * NL * DGRUP;
  for (int idx = threadIdx.x; idx < NL * DGRUP; idx += blockDim.x) {
    int i = idx / DGRUP, c = idx - i * DGRUP;
    float v = 0.f;
    if (c < DGRU) {
      int h = c / HDC;
      v = sp[h][i][0] * sv[0][c] + sp[h][i][1] * sv[1][c] + sp[h][i][2] * sv[2][c];
    }
    orow[idx] = (bf16)v;
  }
}

// ---------------- fused residual-add + LayerNorm ----------------
__global__ void k_add_ln(const float* __restrict__ x, const float* __restrict__ y,
                         const float* __restrict__ g, const float* __restrict__ b,
                         float* __restrict__ outf, bf16* __restrict__ outb,
                         int D, int Kp) {
  int row = blockIdx.x;
  const float* xr = x + (size_t)row * D;
  const float* yr = y + (size_t)row * D;
  __shared__ float srow[DGRUP];
  __shared__ float wsum[4], wsq[4];
  float lsum = 0.f, lsq = 0.f;
  for (int c = threadIdx.x; c < D; c += blockDim.x) {
    float v = xr[c] + yr[c];
    srow[c] = v;
    lsum += v; lsq += v * v;
  }
  for (int o = 32; o; o >>= 1) { lsum += __shfl_down(lsum, o); lsq += __shfl_down(lsq, o); }
  if ((threadIdx.x & 63) == 0) { wsum[threadIdx.x >> 6] = lsum; wsq[threadIdx.x >> 6] = lsq; }
  __syncthreads();
  float tsum = wsum[0] + wsum[1] + wsum[2] + wsum[3];
  float tsq  = wsq[0] + wsq[1] + wsq[2] + wsq[3];
  float mean = tsum / D;
  float var = tsq / D - mean * mean;
  float rstd = rsqrtf(var + 1e-5f);
  for (int c = threadIdx.x; c < Kp; c += blockDim.x) {
    if (c < D) {
      float v = (srow[c] - mean) * rstd * g[c] + b[c];
      if (outf) outf[(size_t)row * D + c] = v;
      if (outb) outb[(size_t)row * Kp + c] = (bf16)v;
    } else if (outb) {
      outb[(size_t)row * Kp + c] = (bf16)0.f;
    }
  }
}

// ---------------- mean over L=3 ----------------
__global__ void k_mean3(const float* __restrict__ enc, bf16* __restrict__ mb) {
  int stride = gridDim.x * blockDim.x;
  int total = NROW * DGRUP;
  for (int i = blockIdx.x * blockDim.x + threadIdx.x; i < total; i += stride) {
    int r = i / DGRUP, c = i - r * DGRUP;
    float v = 0.f;
    if (c < DGRU) {
      const float* e = enc + ((size_t)r * 3) * DGRU + c;
      v = (e[0] + e[DGRU] + e[2 * DGRU]) * (1.f / 3.f);
    }
    mb[i] = (bf16)v;
  }
}

// ---------------- sa attention: seq=100, 8 heads, hd=16, f32 ----------------
__global__ void k_attn_sa(const float* __restrict__ QKV, bf16* __restrict__ out) {
  __shared__ float sQ[NW][16], sK[NW][16], sV[NW][16];
  __shared__ float sS[NW][NW];
  int b = blockIdx.x >> 3, h = blockIdx.x & 7;
  const float* basep = QKV + (size_t)b * NW * 384;
  for (int idx = threadIdx.x; idx < NW * 16; idx += blockDim.x) {
    int w = idx / 16, d = idx - w * 16;
    sQ[w][d] = basep[w * 384 + h * 16 + d];
    sK[w][d] = basep[w * 384 + 128 + h * 16 + d];
    sV[w][d] = basep[w * 384 + 256 + h * 16 + d];
  }
  __syncthreads();
  for (int idx = threadIdx.x; idx < NW * NW; idx += blockDim.x) {
    int q = idx / NW, k = idx - q * NW;
    float s = 0.f;
#pragma unroll
    for (int d = 0; d < 16; d++) s += sQ[q][d] * sK[k][d];
    sS[q][k] = s * 0.25f;  // 1/sqrt(16)
  }
  __syncthreads();
  if (threadIdx.x < NW) {
    int q = threadIdx.x;
    float mx = -1e30f;
    for (int k = 0; k < NW; k++) mx = fmaxf(mx, sS[q][k]);
    float sum = 0.f;
    for (int k = 0; k < NW; k++) { float e = expf(sS[q][k] - mx); sS[q][k] = e; sum += e; }
    float inv = 1.f / sum;
    for (int k = 0; k < NW; k++) sS[q][k] *= inv;
  }
  __syncthreads();
  for (int idx = threadIdx.x; idx < NW * 16; idx += blockDim.x) {
    int q = idx / 16, d = idx - q * 16;
    float o = 0.f;
    for (int k = 0; k < NW; k++) o += sS[q][k] * sV[k][d];
    out[((size_t)b * NW + q) * 128 + h * 16 + d] = (bf16)o;
  }
}

// ---------------- build feats = [g | src_emb | tgt_emb] (+pad to 480) ----------------
__global__ void k_feats(const float* __restrict__ g, const float* __restrict__ node_table,
                        const int* __restrict__ src_idx, const int* __restrict__ tgt_idx,
                        bf16* __restrict__ feats) {
  int stride = gridDim.x * blockDim.x;
  int total = NROW * 480;
  for (int i = blockIdx.x * blockDim.x + threadIdx.x; i < total; i += stride) {
    int r = i / 480, c = i - r * 480;
    int b = r / NW;
    float v = 0.f;
    if (c < 128) v = g[(size_t)r * 128 + c];
    else if (c < 300) v = node_table[(size_t)src_idx[b] * NDF + (c - 128)];
    else if (c < 472) v = node_table[(size_t)tgt_idx[b] * NDF + (c - 300)];
    feats[i] = (bf16)v;
  }
}

// ---------------- final head: sigmoid(fh @ f_W2^T + b2) ----------------
__global__ void k_final(const bf16* __restrict__ fh, const float* __restrict__ f_W2,
                        const float* __restrict__ f_b2, float* __restrict__ out) {
  int row = blockIdx.x * 4 + (threadIdx.x >> 6);
  int lane = threadIdx.x & 63;
  const bf16* fr = fh + (size_t)row * 128;
  float s = 0.f;
  for (int c = lane; c < 128; c += 64) s += (float)fr[c] * f_W2[c];
  for (int o = 32; o; o >>= 1) s += __shfl_down(s, o);
  if (lane == 0) out[row] = 1.f / (1.f + expf(-(s + f_b2[0])));
}

static inline int imin_(int a, int b) { return a < b ? a : b; }
static inline int cdiv_(int a, int b) { return (a + b - 1) / b; }

extern "C" void kernel_launch(void* const* d_in, const int* in_sizes, int n_in,
                              void* d_out, int out_size, void* d_ws, size_t ws_size,
                              hipStream_t stream) {
  (void)in_sizes; (void)n_in; (void)out_size; (void)ws_size;
  const float* node_table = (const float*)d_in[0];
  const float* edge_table = (const float*)d_in[1];
  const float* basis_freq = (const float*)d_in[2];
  const float* phase      = (const float*)d_in[3];
  const float* cat_Wqkv = (const float*)d_in[4];
  const float* cat_bqkv = (const float*)d_in[5];
  const float* cat_Wo   = (const float*)d_in[6];
  const float* cat_bo   = (const float*)d_in[7];
  const float* cat_g1   = (const float*)d_in[8];
  const float* cat_b1   = (const float*)d_in[9];
  const float* cat_W1   = (const float*)d_in[10];
  const float* cat_c1   = (const float*)d_in[11];
  const float* cat_W2   = (const float*)d_in[12];
  const float* cat_c2   = (const float*)d_in[13];
  const float* cat_g2   = (const float*)d_in[14];
  const float* cat_b2   = (const float*)d_in[15];
  const float* sa_Wqkv = (const float*)d_in[16];
  const float* sa_bqkv = (const float*)d_in[17];
  const float* sa_Wo   = (const float*)d_in[18];
  const float* sa_bo   = (const float*)d_in[19];
  const float* sa_g1   = (const float*)d_in[20];
  const float* sa_b1   = (const float*)d_in[21];
  const float* sa_W1   = (const float*)d_in[22];
  const float* sa_c1   = (const float*)d_in[23];
  const float* sa_W2   = (const float*)d_in[24];
  const float* sa_c2   = (const float*)d_in[25];
  const float* sa_g2   = (const float*)d_in[26];
  const float* sa_b2   = (const float*)d_in[27];
  const float* ma_W1 = (const float*)d_in[28];
  const float* ma_b1 = (const float*)d_in[29];
  const float* ma_W2 = (const float*)d_in[30];
  const float* ma_b2 = (const float*)d_in[31];
  const float* f_W1 = (const float*)d_in[32];
  const float* f_b1 = (const float*)d_in[33];
  const float* f_W2 = (const float*)d_in[34];
  const float* f_b2 = (const float*)d_in[35];
  const int* node_idx = (const int*)d_in[36];
  const int* edge_idx = (const int*)d_in[37];
  const float* time_idx = (const float*)d_in[38];
  const int* src_idx = (const int*)d_in[39];
  const int* tgt_idx = (const int*)d_in[40];

  char* basews = (char*)d_ws;
  size_t off = 0;
  auto take = [&](size_t bytes) -> void* {
    void* r = basews + off;
    off += (bytes + 255) & ~(size_t)255;
    return r;
  };

  // bf16 weights (K zero-padded to x32)
  bf16* wqkv_b = (bf16*)take((size_t)2064 * 704 * 2);
  bf16* wo_b   = (bf16*)take((size_t)688 * 704 * 2);
  bf16* w1_b   = (bf16*)take((size_t)4096 * 704 * 2);
  bf16* w2_b   = (bf16*)take((size_t)688 * 4096 * 2);
  bf16* sqkv_b = (bf16*)take((size_t)384 * 128 * 2);
  bf16* swo_b  = (bf16*)take((size_t)128 * 128 * 2);
  bf16* sw1_b  = (bf16*)take((size_t)4096 * 128 * 2);
  bf16* sw2_b  = (bf16*)take((size_t)128 * 4096 * 2);
  bf16* maw1_b = (bf16*)take((size_t)128 * 704 * 2);
  bf16* maw2_b = (bf16*)take((size_t)128 * 128 * 2);
  bf16* fw1_b  = (bf16*)take((size_t)128 * 480 * 2);
  // activations
  float* Xf  = (float*)take((size_t)NTOK * DGRU * 4);
  bf16*  Xb  = (bf16*)take((size_t)NTOK * DGRUP * 2);
  float* qkv = (float*)take((size_t)NTOK * 2064 * 4);
  bf16*  ffn1_b = (bf16*)qkv;                 // reuse (attn consumed qkv first)
  bf16*  attn_b = (bf16*)take((size_t)NTOK * DGRUP * 2);
  float* woo = (float*)take((size_t)NTOK * DGRU * 4);
  float* ffn2o = woo;                         // reuse (LN1 consumed woo first)
  float* h1f = (float*)take((size_t)NTOK * DGRU * 4);
  bf16*  h1b = (bf16*)take((size_t)NTOK * DGRUP * 2);
  float* encf = Xf;                           // reuse (Xf dead after LN1)
  bf16*  meanb = (bf16*)take((size_t)NROW * DGRUP * 2);
  bf16*  mah_b = (bf16*)take((size_t)NROW * 128 * 2);
  float* gf = (float*)take((size_t)NROW * 128 * 4);
  bf16*  gb = (bf16*)take((size_t)NROW * 128 * 2);
  float* qkvsa = (float*)take((size_t)NROW * 384 * 4);
  bf16*  attnsa_b = (bf16*)take((size_t)NROW * 128 * 2);
  float* sawoo = (float*)take((size_t)NROW * 128 * 4);
  float* sah1f = (float*)take((size_t)NROW * 128 * 4);
  bf16*  sah1b = (bf16*)take((size_t)NROW * 128 * 2);
  bf16*  saffn1_b = (bf16*)take((size_t)NROW * 4096 * 2);
  float* saffn2o = (float*)take((size_t)NROW * 128 * 4);
  float* saencf = (float*)take((size_t)NROW * 128 * 4);
  bf16*  feats_b = (bf16*)take((size_t)NROW * 480 * 2);
  bf16*  fh_b = (bf16*)take((size_t)NROW * 128 * 2);

  auto cvt = [&](const float* s, bf16* d, int R, int K, int Kp) {
    int n = R * Kp;
    k_cvt_pad<<<imin_(cdiv_(n, 256), 8192), 256, 0, stream>>>(s, d, R, K, Kp);
  };
  cvt(cat_Wqkv, wqkv_b, 2064, 688, 704);
  cvt(cat_Wo,   wo_b,   688, 688, 704);
  cvt(cat_W1,   w1_b,   4096, 688, 704);
  cvt(cat_W2,   w2_b,   688, 4096, 4096);
  cvt(sa_Wqkv,  sqkv_b, 384, 128, 128);
  cvt(sa_Wo,    swo_b,  128, 128, 128);
  cvt(sa_W1,    sw1_b,  4096, 128, 128);
  cvt(sa_W2,    sw2_b,  128, 4096, 4096);
  cvt(ma_W1,    maw1_b, 128, 688, 704);
  cvt(ma_W2,    maw2_b, 128, 128, 128);
  cvt(f_W1,     fw1_b,  128, 472, 480);

  k_build_X<<<NTOK, 256, 0, stream>>>(node_table, edge_table, basis_freq, phase,
                                      node_idx, edge_idx, time_idx, Xf, Xb);

  auto gemm = [&](const bf16* A, const bf16* Bw, const float* bias,
                  float* Cf, bf16* Cb, int M, int N, int Kp, int relu) {
    dim3 grid(cdiv_(N, BN), M / BM);
    k_gemm<<<grid, 256, 0, stream>>>(A, Bw, bias, Cf, Cb, M, N, Kp, relu);
  };

  // ---- cat encoder (tokens = 19200, D = 688) ----
  gemm(Xb, wqkv_b, cat_bqkv, qkv, nullptr, NTOK, 2064, 704, 0);
  k_attn_cat<<<NROW, 256, 0, stream>>>(qkv, attn_b);
  gemm(attn_b, wo_b, cat_bo, woo, nullptr, NTOK, 688, 704, 0);
  k_add_ln<<<NTOK, 256, 0, stream>>>(Xf, woo, cat_g1, cat_b1, h1f, h1b, DGRU, DGRUP);
  gemm(h1b, w1_b, cat_c1, nullptr, ffn1_b, NTOK, 4096, 704, 1);
  gemm(ffn1_b, w2_b, cat_c2, ffn2o, nullptr, NTOK, 688, 4096, 0);
  k_add_ln<<<NTOK, 256, 0, stream>>>(h1f, ffn2o, cat_g2, cat_b2, encf, nullptr, DGRU, DGRU);
  k_mean3<<<imin_(cdiv_(NROW * DGRUP, 256), 8192), 256, 0, stream>>>(encf, meanb);

  // ---- ma MLP ----
  gemm(meanb, maw1_b, ma_b1, nullptr, mah_b, NROW, 128, 704, 1);
  gemm(mah_b, maw2_b, ma_b2, gf, gb, NROW, 128, 128, 0);

  // ---- sa encoder (64 x 100 tokens, D = 128) ----
  gemm(gb, sqkv_b, sa_bqkv, qkvsa, nullptr, NROW, 384, 128, 0);
  k_attn_sa<<<NB * 8, 256, 0, stream>>>(qkvsa, attnsa_b);
  gemm(attnsa_b, swo_b, sa_bo, sawoo, nullptr, NROW, 128, 128, 0);
  k_add_ln<<<NROW, 256, 0, stream>>>(gf, sawoo, sa_g1, sa_b1, sah1f, sah1b, 128, 128);
  gemm(sah1b, sw1_b, sa_c1, nullptr, saffn1_b, NROW, 4096, 128, 1);
  gemm(saffn1_b, sw2_b, sa_c2, saffn2o, nullptr, NROW, 128, 4096, 0);
  k_add_ln<<<NROW, 256, 0, stream>>>(sah1f, saffn2o, sa_g2, sa_b2, saencf, nullptr, 128, 128);

  // ---- head ----
  k_feats<<<imin_(cdiv_(NROW * 480, 256), 8192), 256, 0, stream>>>(saencf, node_table, src_idx, tgt_idx, feats_b);
  gemm(feats_b, fw1_b, f_b1, nullptr, fh_b, NROW, 128, 480, 1);
  k_final<<<NROW / 4, 256, 0, stream>>>(fh_b, f_W2, f_b2, (float*)d_out);
}